// Round 12
// baseline (355.120 us; speedup 1.0000x reference)
//
#include <hip/hip_runtime.h>
#include <hip/hip_fp16.h>
#include <math.h>

#define NN     40000
#define NT0    20000
#define NE     640000
#define NHOPS  8
#define RCAP   64
#define NSLICE 8
#define SLICEN (NN / NSLICE)
#define SL2    ((size_t)(NN + 1) * 64)      // elems per channel-slice plane (128B rows)

typedef _Float16 f16x8 __attribute__((ext_vector_type(8)));
typedef float    f32x4 __attribute__((ext_vector_type(4)));

// ---------------- init: csr fill + counter zero + g dummy-row zero --------------
__global__ __launch_bounds__(256) void init_kernel(unsigned* __restrict__ csr2,
                                                   unsigned* __restrict__ counters,
                                                   unsigned* __restrict__ gbase)
{
    const unsigned pat = (40000u << 16) | 40000u;
    int tid = blockIdx.x * 256 + threadIdx.x;          // 2048 blocks -> 524288 threads
    for (int u = tid; u < SLICEN * RCAP * NSLICE / 2; u += 524288) csr2[u] = pat;
    if (tid < 80000) counters[tid] = 0u;               // odeg (40000) + cnt (40000)
    if (tid < 18 * 32) {                               // dummy row NN: 9 bufs x 2 slices
        int plane = tid >> 5, j = tid & 31;
        gbase[(size_t)plane * (SL2 >> 1) + ((size_t)NN << 5) + j] = 0u;
    }
}

// ---------------- fused degree count + bucket, XCD-sliced ----------------
__global__ void degbucket_kernel(const int* __restrict__ src, const int* __restrict__ dst,
                                 unsigned* __restrict__ out_deg, unsigned* __restrict__ cnt,
                                 unsigned short* __restrict__ csr, int E)
{
    int slice = blockIdx.x & 7;
    int lo = slice * SLICEN, hi = lo + SLICEN;
    int pb = blockIdx.x >> 3;
    int start = pb * 256 + threadIdx.x;
    for (int e = start; e < E; e += 65536) {
        int s = __builtin_nontemporal_load(src + e);
        int d = __builtin_nontemporal_load(dst + e);
        if (s >= lo && s < hi) atomicAdd(&out_deg[s], 1u);
        if (d >= lo && d < hi) {
            unsigned p = atomicAdd(&cnt[d], 1u);
            if (p < RCAP) csr[(d << 6) + (int)p] = (unsigned short)s;
        }
    }
}

// ---------------- norms ----------------
__global__ void norm_kernel(const unsigned* __restrict__ out_deg, const unsigned* __restrict__ in_deg,
                            float* __restrict__ ns, float* __restrict__ nsd,
                            float* __restrict__ rns, int n)
{
    int i = blockIdx.x * blockDim.x + threadIdx.x;
    if (i >= n) return;
    float od = fmaxf((float)out_deg[i], 1.0f);
    float s = rsqrtf(od);
    float d = rsqrtf(fmaxf((float)in_deg[i], 1.0f));
    ns[i] = s; nsd[i] = s * d; rns[i] = sqrtf(od);
}

// ---------------- W[K][128] f32 -> WT[128][K] fp16 (tiled transpose) ----------
__global__ __launch_bounds__(256) void wtrans_kernel(const float* __restrict__ W,
                                                     _Float16* __restrict__ WT, int K)
{
    __shared__ float t[32][33];
    int bk = blockIdx.x * 32;
    int bn = blockIdx.y * 32;
    int tx = threadIdx.x & 31, ty4 = (threadIdx.x >> 5) * 4;
#pragma unroll
    for (int i = 0; i < 4; ++i)
        t[ty4 + i][tx] = W[(size_t)(bk + ty4 + i) * 128 + bn + tx];
    __syncthreads();
#pragma unroll
    for (int i = 0; i < 4; ++i)
        WT[(size_t)(bn + ty4 + i) * K + bk + tx] = (_Float16)t[tx][ty4 + i];
}

// ---------------- MFMA projection: g0 = fp16((feat @ W + b) * ns), sliced layout --
template<int K>
__global__ __launch_bounds__(256) void projmm_kernel(
    const float* __restrict__ feat, const _Float16* __restrict__ WT,
    const float* __restrict__ b, const float* __restrict__ ns,
    __half* __restrict__ g0, int row0, int M)
{
    constexpr int LDB = K + 8;
    __shared__ _Float16 BT[128 * LDB];
    int tid = threadIdx.x;
    for (int idx = tid * 8; idx < 128 * K; idx += 256 * 8) {
        int n = idx / K, k = idx % K;
        *(f16x8*)(&BT[n * LDB + k]) = *(const f16x8*)(&WT[n * K + k]);
    }
    __syncthreads();

    int wave = tid >> 6, lane = tid & 63;
    int rb = blockIdx.x * 64 + wave * 16;
    int lr = lane & 15, lk = lane >> 4;

    f32x4 acc[8] = {};
    int arow = rb + lr; if (arow >= M) arow = M - 1;
    const float* afp = feat + (size_t)arow * K;

    for (int k0 = 0; k0 < K; k0 += 32) {
        float4 fa = *(const float4*)(afp + k0 + lk * 8);
        float4 fb = *(const float4*)(afp + k0 + lk * 8 + 4);
        f16x8 a;
        a[0] = (_Float16)fa.x; a[1] = (_Float16)fa.y;
        a[2] = (_Float16)fa.z; a[3] = (_Float16)fa.w;
        a[4] = (_Float16)fb.x; a[5] = (_Float16)fb.y;
        a[6] = (_Float16)fb.z; a[7] = (_Float16)fb.w;
#pragma unroll
        for (int t = 0; t < 8; ++t) {
            f16x8 bf = *(const f16x8*)(&BT[(t * 16 + lr) * LDB + k0 + lk * 8]);
            acc[t] = __builtin_amdgcn_mfma_f32_16x16x32_f16(a, bf, acc[t], 0, 0, 0);
        }
    }

    float bv[8];
#pragma unroll
    for (int t = 0; t < 8; ++t) bv[t] = b[t * 16 + lr];
#pragma unroll
    for (int reg = 0; reg < 4; ++reg) {
        int r = rb + lk * 4 + reg;
        if (r < M) {
            float s = ns[row0 + r];
            int row = row0 + r;
#pragma unroll
            for (int t = 0; t < 8; ++t) {
                int sl = t >> 2;                    // cols 0-63 slice0, 64-127 slice1
                g0[(size_t)sl * SL2 + ((size_t)row << 6) + (t & 3) * 16 + lr] =
                    __float2half((acc[t][reg] + bv[t]) * s);
            }
        }
    }
}

// ---------------- one hop, channel-sliced: slice = blockIdx&1 (XCD pinning) ------
// wave per node per slice; 8 edge-subgroups x 8 lanes x 16B = 128B row.
__global__ __launch_bounds__(256) void hop_kernel(
    const __half* __restrict__ gc, __half* __restrict__ gn,
    const unsigned* __restrict__ ideg, const unsigned short* __restrict__ csr,
    const float* __restrict__ nsd)
{
    int slice = blockIdx.x & 1;
    int node = (blockIdx.x >> 1) * 4 + (threadIdx.x >> 6);
    int lane = threadIdx.x & 63;
    int sub = lane >> 3;                  // edge slot 0..7
    int ch8 = lane & 7;                   // 16B chunk within the 128B slice-row
    int dd = (int)ideg[node];
    int len = dd > RCAP ? RCAP : ((dd + 15) & ~15);
    int beg = node << 6;
    int end = beg + len;

    const __half* gsl = gc + (size_t)slice * SL2;
    float a[8] = {0.f, 0.f, 0.f, 0.f, 0.f, 0.f, 0.f, 0.f};
    for (int base = beg; base < end; base += 16) {
        int i = base + sub;
        int s0 = (int)csr[i];
        int s1 = (int)csr[i + 8];
        int4 v0 = *(const int4*)(gsl + ((size_t)s0 << 6) + (ch8 << 3));
        int4 v1 = *(const int4*)(gsl + ((size_t)s1 << 6) + (ch8 << 3));
        float2 f;
        f = __half22float2(*(__half2*)&v0.x); a[0] += f.x; a[1] += f.y;
        f = __half22float2(*(__half2*)&v0.y); a[2] += f.x; a[3] += f.y;
        f = __half22float2(*(__half2*)&v0.z); a[4] += f.x; a[5] += f.y;
        f = __half22float2(*(__half2*)&v0.w); a[6] += f.x; a[7] += f.y;
        f = __half22float2(*(__half2*)&v1.x); a[0] += f.x; a[1] += f.y;
        f = __half22float2(*(__half2*)&v1.y); a[2] += f.x; a[3] += f.y;
        f = __half22float2(*(__half2*)&v1.z); a[4] += f.x; a[5] += f.y;
        f = __half22float2(*(__half2*)&v1.w); a[6] += f.x; a[7] += f.y;
    }
    // reduce across the 8 edge-subgroups (xor lanes 8, 16, 32)
#pragma unroll
    for (int j = 0; j < 8; ++j) {
        a[j] += __shfl_xor(a[j], 8);
        a[j] += __shfl_xor(a[j], 16);
        a[j] += __shfl_xor(a[j], 32);
    }
    if (sub == 0) {
        float k = nsd[node];
        __half2 h0 = __float22half2_rn(make_float2(a[0] * k, a[1] * k));
        __half2 h1 = __float22half2_rn(make_float2(a[2] * k, a[3] * k));
        __half2 h2 = __float22half2_rn(make_float2(a[4] * k, a[5] * k));
        __half2 h3 = __float22half2_rn(make_float2(a[6] * k, a[7] * k));
        int4 w;
        w.x = *(int*)&h0; w.y = *(int*)&h1; w.z = *(int*)&h2; w.w = *(int*)&h3;
        *(int4*)(gn + (size_t)slice * SL2 + ((size_t)node << 6) + (ch8 << 3)) = w;
    }
}

// ---------------- gsum+LN0: xn = LN0((sum_k g_k) * rns / 9), fp16 out ----------
__global__ __launch_bounds__(256) void gsum_ln0_kernel(
    const __half* __restrict__ g, const float* __restrict__ rns,
    const float* __restrict__ ln0g, const float* __restrict__ ln0b,
    __half* __restrict__ xn)
{
    int c = blockIdx.x * 256 + threadIdx.x;
    int node = c >> 4, ch0 = (c & 15) << 3;
    int slice = ch0 >> 6, co = ch0 & 63;
    size_t base = (size_t)slice * SL2 + ((size_t)node << 6) + co;
    float s8[8] = {0,0,0,0,0,0,0,0};
#pragma unroll
    for (int k = 0; k < 9; ++k) {
        int4 v = *(const int4*)(g + (size_t)k * 2 * SL2 + base);
        float2 f;
        f = __half22float2(*(__half2*)&v.x); s8[0] += f.x; s8[1] += f.y;
        f = __half22float2(*(__half2*)&v.y); s8[2] += f.x; s8[3] += f.y;
        f = __half22float2(*(__half2*)&v.z); s8[4] += f.x; s8[5] += f.y;
        f = __half22float2(*(__half2*)&v.w); s8[6] += f.x; s8[7] += f.y;
    }
    float sc = rns[node] * (1.0f / 9.0f);
#pragma unroll
    for (int i = 0; i < 8; ++i) s8[i] *= sc;

    float t = 0.f;
#pragma unroll
    for (int i = 0; i < 8; ++i) t += s8[i];
#pragma unroll
    for (int m = 1; m < 16; m <<= 1) t += __shfl_xor(t, m);
    float mean = t * (1.0f / 128.0f);
    float q = 0.f;
#pragma unroll
    for (int i = 0; i < 8; ++i) { s8[i] -= mean; q += s8[i] * s8[i]; }
#pragma unroll
    for (int m = 1; m < 16; m <<= 1) q += __shfl_xor(q, m);
    float rstd = rsqrtf(q * (1.0f / 128.0f) + 1e-5f);
    float4 ga = *(const float4*)(ln0g + ch0);
    float4 gA = *(const float4*)(ln0g + ch0 + 4);
    float4 ba = *(const float4*)(ln0b + ch0);
    float4 bA = *(const float4*)(ln0b + ch0 + 4);
    __half2 h0 = __float22half2_rn(make_float2(s8[0]*rstd*ga.x + ba.x, s8[1]*rstd*ga.y + ba.y));
    __half2 h1 = __float22half2_rn(make_float2(s8[2]*rstd*ga.z + ba.z, s8[3]*rstd*ga.w + ba.w));
    __half2 h2 = __float22half2_rn(make_float2(s8[4]*rstd*gA.x + bA.x, s8[5]*rstd*gA.y + bA.y));
    __half2 h3 = __float22half2_rn(make_float2(s8[6]*rstd*gA.z + bA.z, s8[7]*rstd*gA.w + bA.w));
    int4 w;
    w.x = *(int*)&h0; w.y = *(int*)&h1; w.z = *(int*)&h2; w.w = *(int*)&h3;
    *(int4*)(xn + ((size_t)node << 7) + ch0) = w;
}

// ---------------- mm2: y = ELU(xn@WpT+bp); LN1; logits = yn@WoT+bo; L2 norm ------
__global__ __launch_bounds__(256) void mm2_kernel(
    const __half* __restrict__ xn, const _Float16* __restrict__ WpT,
    const float* __restrict__ bp,
    const float* __restrict__ ln1g, const float* __restrict__ ln1b,
    const float* __restrict__ Wo, const float* __restrict__ bo,
    float* __restrict__ out)
{
    constexpr int LDB = 136;
    __shared__ _Float16 BT[128 * LDB];
    __shared__ _Float16 WoT[16 * LDB];
    __shared__ _Float16 YN[64 * LDB];
    int tid = threadIdx.x;
    for (int idx = tid * 8; idx < 128 * 128; idx += 256 * 8) {
        int n = idx >> 7, k = idx & 127;
        *(f16x8*)(&BT[n * LDB + k]) = *(const f16x8*)(&WpT[n * 128 + k]);
    }
    for (int idx = tid; idx < 2048; idx += 256) {
        int k = idx >> 4, c = idx & 15;
        WoT[c * LDB + k] = (_Float16)Wo[idx];
    }
    __syncthreads();

    int wave = tid >> 6, lane = tid & 63;
    int lr = lane & 15, lk = lane >> 4;
    int rb = blockIdx.x * 64 + wave * 16;

    f32x4 acc[8] = {};
    const __half* ap = xn + ((size_t)(rb + lr) << 7);
    for (int k0 = 0; k0 < 128; k0 += 32) {
        f16x8 a = *(const f16x8*)(ap + k0 + lk * 8);
#pragma unroll
        for (int t = 0; t < 8; ++t) {
            f16x8 bf = *(const f16x8*)(&BT[(t * 16 + lr) * LDB + k0 + lk * 8]);
            acc[t] = __builtin_amdgcn_mfma_f32_16x16x32_f16(a, bf, acc[t], 0, 0, 0);
        }
    }

    float bv[8], hg[8], hb[8];
#pragma unroll
    for (int t = 0; t < 8; ++t) {
        bv[t] = bp[t * 16 + lr];
        hg[t] = ln1g[t * 16 + lr];
        hb[t] = ln1b[t * 16 + lr];
    }
#pragma unroll
    for (int reg = 0; reg < 4; ++reg) {
        float y[8], S = 0.f;
#pragma unroll
        for (int t = 0; t < 8; ++t) {
            float v = acc[t][reg] + bv[t];
            v = v > 0.f ? v : (expf(v) - 1.f);
            y[t] = v; S += v;
        }
#pragma unroll
        for (int m = 1; m < 16; m <<= 1) S += __shfl_xor(S, m);
        float mean = S * (1.0f / 128.0f);
        float q = 0.f;
#pragma unroll
        for (int t = 0; t < 8; ++t) { y[t] -= mean; q += y[t] * y[t]; }
#pragma unroll
        for (int m = 1; m < 16; m <<= 1) q += __shfl_xor(q, m);
        float rstd = rsqrtf(q * (1.0f / 128.0f) + 1e-5f);
        int row_l = wave * 16 + lk * 4 + reg;
#pragma unroll
        for (int t = 0; t < 8; ++t)
            YN[row_l * LDB + t * 16 + lr] = (_Float16)(y[t] * rstd * hg[t] + hb[t]);
    }
    __syncthreads();

    f32x4 p = {};
    const _Float16* yrow = &YN[(wave * 16 + lr) * LDB];
    for (int k0 = 0; k0 < 128; k0 += 32) {
        f16x8 a = *(const f16x8*)(yrow + k0 + lk * 8);
        f16x8 bf = *(const f16x8*)(&WoT[lr * LDB + k0 + lk * 8]);
        p = __builtin_amdgcn_mfma_f32_16x16x32_f16(a, bf, p, 0, 0, 0);
    }
    float bol = bo[lr];
#pragma unroll
    for (int reg = 0; reg < 4; ++reg) {
        float logit = p[reg] + bol;
        float ss = logit * logit;
#pragma unroll
        for (int m = 1; m < 16; m <<= 1) ss += __shfl_xor(ss, m);
        float rinv = 1.0f / fmaxf(sqrtf(ss), 1e-12f);
        int row = rb + lk * 4 + reg;
        out[(size_t)row * 16 + lr] = logit * rinv;
    }
}

// ---------------- launch ----------------
extern "C" void kernel_launch(void* const* d_in, const int* in_sizes, int n_in,
                              void* d_out, int out_size, void* d_ws, size_t ws_size,
                              hipStream_t stream)
{
    const float* feat0 = (const float*)d_in[0];
    const float* feat1 = (const float*)d_in[1];
    const int*   src   = (const int*)d_in[2];
    const int*   dst   = (const int*)d_in[3];
    const float* W0    = (const float*)d_in[4];
    const float* b0    = (const float*)d_in[5];
    const float* W1    = (const float*)d_in[6];
    const float* b1    = (const float*)d_in[7];
    const float* ln0_g = (const float*)d_in[8];
    const float* ln0_b = (const float*)d_in[9];
    const float* ln1_g = (const float*)d_in[10];
    const float* ln1_b = (const float*)d_in[11];
    const float* Wp    = (const float*)d_in[12];
    const float* bp    = (const float*)d_in[13];
    const float* Wo    = (const float*)d_in[14];
    const float* bo    = (const float*)d_in[15];
    float* out = (float*)d_out;

    char* ws = (char*)d_ws;
    __half*         gbuf = (__half*)(ws + 0);           // 9 * 2 * SL2 * 2B = 92,162,304
    float*          ns   = (float*)(ws + 92162304);
    float*          nsd  = (float*)(ws + 92322304);
    float*          rns  = (float*)(ws + 92482304);
    unsigned*       odeg = (unsigned*)(ws + 92642304);  // odeg+cnt contiguous 320KB
    unsigned*       cnt  = (unsigned*)(ws + 92802304);
    unsigned short* csr  = (unsigned short*)(ws + 92962304); // 5,120,000
    __half*         xbuf = (__half*)(ws + 92962304);    // overlay (csr dead after hops)
    _Float16*       WT0  = (_Float16*)(ws + 103202304);
    _Float16*       WT1  = (_Float16*)(ws + 103267840);
    _Float16*       WpT  = (_Float16*)(ws + 103300608);
    // total ~103.3 MB

    wtrans_kernel<<<dim3(8, 4), 256, 0, stream>>>(W0, WT0, 256);
    wtrans_kernel<<<dim3(4, 4), 256, 0, stream>>>(W1, WT1, 128);
    wtrans_kernel<<<dim3(4, 4), 256, 0, stream>>>(Wp, WpT, 128);

    init_kernel<<<2048, 256, 0, stream>>>((unsigned*)csr, odeg, (unsigned*)gbuf);
    degbucket_kernel<<<2048, 256, 0, stream>>>(src, dst, odeg, cnt, csr, NE);
    norm_kernel<<<(NN + 255) / 256, 256, 0, stream>>>(odeg, cnt, ns, nsd, rns, NN);

    projmm_kernel<256><<<(NT0 + 63) / 64, 256, 0, stream>>>(feat0, WT0, b0, ns, gbuf, 0, NT0);
    projmm_kernel<128><<<(NT0 + 63) / 64, 256, 0, stream>>>(feat1, WT1, b1, ns, gbuf, NT0, NT0);

    for (int h = 0; h < NHOPS; ++h) {
        hop_kernel<<<2 * (NN / 4), 256, 0, stream>>>(gbuf + (size_t)h * 2 * SL2,
                                                     gbuf + (size_t)(h + 1) * 2 * SL2,
                                                     cnt, csr, nsd);
    }

    gsum_ln0_kernel<<<2500, 256, 0, stream>>>(gbuf, rns, ln0_g, ln0_b, xbuf);
    mm2_kernel<<<NN / 64, 256, 0, stream>>>(xbuf, WpT, bp, ln1_g, ln1_b, Wo, bo, out);
}

// Round 13
// 308.914 us; speedup vs baseline: 1.1496x; 1.1496x over previous
//
#include <hip/hip_runtime.h>
#include <hip/hip_fp16.h>
#include <math.h>

#define NN     40000
#define NT0    20000
#define NE     640000
#define NHOPS  8
#define RCAP   64
#define NSLICE 8
#define SLICEN (NN / NSLICE)                  // 5000
#define BCAP   84000                          // bucket capacity (80000 avg + 15 sigma)
#define GSTRIDE ((size_t)(NN + 1) * 128)      // elems per g buffer (row NN = dummy zero)

typedef _Float16 f16x8 __attribute__((ext_vector_type(8)));
typedef float    f32x4 __attribute__((ext_vector_type(4)));

// ---------------- init: csr fill + counter/bptr zero + g dummy-row zero ----------
__global__ __launch_bounds__(256) void init_kernel(unsigned* __restrict__ csr2,
                                                   unsigned* __restrict__ counters,
                                                   unsigned* __restrict__ gbase)
{
    const unsigned pat = (40000u << 16) | 40000u;
    int tid = blockIdx.x * 256 + threadIdx.x;          // 2048*256 = 524288 threads
    for (int u = tid; u < NN * RCAP / 2; u += 524288) csr2[u] = pat;
    if (tid < 80008) counters[tid] = 0u;               // odeg(40000)+cnt(40000)+bptr(8)
    if (tid < 9 * 64) {
        int k = tid >> 6, j = tid & 63;
        gbase[(size_t)k * (GSTRIDE / 2) + ((size_t)NN << 6) + j] = 0u;
    }
}

// ---------------- phase A: partition edges into 8 dst-slice buckets --------------
// one edge per thread (grid 2500 x 256 = 640000); LDS histogram -> 8 atomics/block
__global__ __launch_bounds__(256) void partition_kernel(
    const int* __restrict__ src, const int* __restrict__ dst,
    unsigned* __restrict__ odeg, unsigned* __restrict__ bptr,
    unsigned* __restrict__ ebuf)
{
    __shared__ unsigned lhist[8];
    __shared__ unsigned gbase[8];
    int tid = threadIdx.x;
    if (tid < 8) lhist[tid] = 0u;
    __syncthreads();
    int e = blockIdx.x * 256 + tid;
    int s = src[e], d = dst[e];
    atomicAdd(&odeg[s], 1u);
    int b = d / SLICEN;
    unsigned r = atomicAdd(&lhist[b], 1u);   // rank within (block, bucket)
    __syncthreads();
    if (tid < 8) gbase[tid] = atomicAdd(&bptr[tid], lhist[tid]);
    __syncthreads();
    unsigned pos = gbase[b] + r;
    if (pos < BCAP) ebuf[b * BCAP + pos] = ((unsigned)s << 16) | (unsigned)d;
}

// ---------------- phase B: per-slice scatter into csr (XCD-local) ----------------
__global__ void scatter_kernel(const unsigned* __restrict__ ebuf,
                               const unsigned* __restrict__ bptr,
                               unsigned* __restrict__ cnt,
                               unsigned short* __restrict__ csr)
{
    int slice = blockIdx.x & 7;
    int pb = blockIdx.x >> 3;
    unsigned count = bptr[slice];
    const unsigned* eb = ebuf + slice * BCAP;
    for (unsigned i = pb * 256 + threadIdx.x; i < count; i += 65536) {
        unsigned pk = eb[i];
        int d = (int)(pk & 0xFFFFu);
        int s = (int)(pk >> 16);
        unsigned p = atomicAdd(&cnt[d], 1u);
        if (p < RCAP) csr[(d << 6) + (int)p] = (unsigned short)s;
    }
}

// ---------------- norms ----------------
__global__ void norm_kernel(const unsigned* __restrict__ out_deg, const unsigned* __restrict__ in_deg,
                            float* __restrict__ ns, float* __restrict__ nsd,
                            float* __restrict__ rns, int n)
{
    int i = blockIdx.x * blockDim.x + threadIdx.x;
    if (i >= n) return;
    float od = fmaxf((float)out_deg[i], 1.0f);
    float s = rsqrtf(od);
    float d = rsqrtf(fmaxf((float)in_deg[i], 1.0f));
    ns[i] = s; nsd[i] = s * d; rns[i] = sqrtf(od);
}

// ---------------- W[K][128] f32 -> WT[128][K] fp16 (tiled transpose) ----------
__global__ __launch_bounds__(256) void wtrans_kernel(const float* __restrict__ W,
                                                     _Float16* __restrict__ WT, int K)
{
    __shared__ float t[32][33];
    int bk = blockIdx.x * 32;
    int bn = blockIdx.y * 32;
    int tx = threadIdx.x & 31, ty4 = (threadIdx.x >> 5) * 4;
#pragma unroll
    for (int i = 0; i < 4; ++i)
        t[ty4 + i][tx] = W[(size_t)(bk + ty4 + i) * 128 + bn + tx];
    __syncthreads();
#pragma unroll
    for (int i = 0; i < 4; ++i)
        WT[(size_t)(bn + ty4 + i) * K + bk + tx] = (_Float16)t[tx][ty4 + i];
}

// ---------------- MFMA projection: g0[row0+r] = fp16((feat @ W + b) * ns) --------
template<int K>
__global__ __launch_bounds__(256) void projmm_kernel(
    const float* __restrict__ feat, const _Float16* __restrict__ WT,
    const float* __restrict__ b, const float* __restrict__ ns,
    __half* __restrict__ g0, int row0, int M)
{
    constexpr int LDB = K + 8;
    __shared__ _Float16 BT[128 * LDB];
    int tid = threadIdx.x;
    for (int idx = tid * 8; idx < 128 * K; idx += 256 * 8) {
        int n = idx / K, k = idx % K;
        *(f16x8*)(&BT[n * LDB + k]) = *(const f16x8*)(&WT[n * K + k]);
    }
    __syncthreads();

    int wave = tid >> 6, lane = tid & 63;
    int rb = blockIdx.x * 64 + wave * 16;
    int lr = lane & 15, lk = lane >> 4;

    f32x4 acc[8] = {};
    int arow = rb + lr; if (arow >= M) arow = M - 1;
    const float* afp = feat + (size_t)arow * K;

    for (int k0 = 0; k0 < K; k0 += 32) {
        float4 fa = *(const float4*)(afp + k0 + lk * 8);
        float4 fb = *(const float4*)(afp + k0 + lk * 8 + 4);
        f16x8 a;
        a[0] = (_Float16)fa.x; a[1] = (_Float16)fa.y;
        a[2] = (_Float16)fa.z; a[3] = (_Float16)fa.w;
        a[4] = (_Float16)fb.x; a[5] = (_Float16)fb.y;
        a[6] = (_Float16)fb.z; a[7] = (_Float16)fb.w;
#pragma unroll
        for (int t = 0; t < 8; ++t) {
            f16x8 bf = *(const f16x8*)(&BT[(t * 16 + lr) * LDB + k0 + lk * 8]);
            acc[t] = __builtin_amdgcn_mfma_f32_16x16x32_f16(a, bf, acc[t], 0, 0, 0);
        }
    }

    float bv[8];
#pragma unroll
    for (int t = 0; t < 8; ++t) bv[t] = b[t * 16 + lr];
#pragma unroll
    for (int reg = 0; reg < 4; ++reg) {
        int r = rb + lk * 4 + reg;
        if (r < M) {
            float s = ns[row0 + r];
            size_t base = ((size_t)(row0 + r)) << 7;
#pragma unroll
            for (int t = 0; t < 8; ++t)
                g0[base + t * 16 + lr] = __float2half((acc[t][reg] + bv[t]) * s);
        }
    }
}

// ---------------- one hop: wave per node; 4 subgroups x 16 lanes x 16B ----------
__global__ __launch_bounds__(256) void hop_kernel(
    const __half* __restrict__ gc, __half* __restrict__ gn,
    const unsigned* __restrict__ ideg, const unsigned short* __restrict__ csr,
    const float* __restrict__ nsd)
{
    int node = blockIdx.x * 4 + (threadIdx.x >> 6);
    int lane = threadIdx.x & 63;
    int sub = lane >> 4;
    int ch8 = lane & 15;
    int dd = (int)ideg[node];
    int len = dd > RCAP ? RCAP : ((dd + 15) & ~15);
    int beg = node << 6;
    int end = beg + len;

    float a[8] = {0.f, 0.f, 0.f, 0.f, 0.f, 0.f, 0.f, 0.f};
    for (int base = beg; base < end; base += 16) {
        int i = base + sub;
        int s0 = (int)csr[i];
        int s1 = (int)csr[i + 4];
        int s2 = (int)csr[i + 8];
        int s3 = (int)csr[i + 12];
        int4 v0 = *(const int4*)(gc + ((size_t)s0 << 7) + (ch8 << 3));
        int4 v1 = *(const int4*)(gc + ((size_t)s1 << 7) + (ch8 << 3));
        int4 v2 = *(const int4*)(gc + ((size_t)s2 << 7) + (ch8 << 3));
        int4 v3 = *(const int4*)(gc + ((size_t)s3 << 7) + (ch8 << 3));
        float2 f;
        f = __half22float2(*(__half2*)&v0.x); a[0] += f.x; a[1] += f.y;
        f = __half22float2(*(__half2*)&v0.y); a[2] += f.x; a[3] += f.y;
        f = __half22float2(*(__half2*)&v0.z); a[4] += f.x; a[5] += f.y;
        f = __half22float2(*(__half2*)&v0.w); a[6] += f.x; a[7] += f.y;
        f = __half22float2(*(__half2*)&v1.x); a[0] += f.x; a[1] += f.y;
        f = __half22float2(*(__half2*)&v1.y); a[2] += f.x; a[3] += f.y;
        f = __half22float2(*(__half2*)&v1.z); a[4] += f.x; a[5] += f.y;
        f = __half22float2(*(__half2*)&v1.w); a[6] += f.x; a[7] += f.y;
        f = __half22float2(*(__half2*)&v2.x); a[0] += f.x; a[1] += f.y;
        f = __half22float2(*(__half2*)&v2.y); a[2] += f.x; a[3] += f.y;
        f = __half22float2(*(__half2*)&v2.z); a[4] += f.x; a[5] += f.y;
        f = __half22float2(*(__half2*)&v2.w); a[6] += f.x; a[7] += f.y;
        f = __half22float2(*(__half2*)&v3.x); a[0] += f.x; a[1] += f.y;
        f = __half22float2(*(__half2*)&v3.y); a[2] += f.x; a[3] += f.y;
        f = __half22float2(*(__half2*)&v3.z); a[4] += f.x; a[5] += f.y;
        f = __half22float2(*(__half2*)&v3.w); a[6] += f.x; a[7] += f.y;
    }
#pragma unroll
    for (int j = 0; j < 8; ++j) {
        a[j] += __shfl_xor(a[j], 16);
        a[j] += __shfl_xor(a[j], 32);
    }
    if (sub == 0) {
        float k = nsd[node];
        __half2 h0 = __float22half2_rn(make_float2(a[0] * k, a[1] * k));
        __half2 h1 = __float22half2_rn(make_float2(a[2] * k, a[3] * k));
        __half2 h2 = __float22half2_rn(make_float2(a[4] * k, a[5] * k));
        __half2 h3 = __float22half2_rn(make_float2(a[6] * k, a[7] * k));
        int4 w;
        w.x = *(int*)&h0; w.y = *(int*)&h1; w.z = *(int*)&h2; w.w = *(int*)&h3;
        *(int4*)(gn + ((size_t)node << 7) + (ch8 << 3)) = w;
    }
}

// ---------------- gsum+LN0: xn = LN0((sum_k g_k) * rns / 9), fp16 out ----------
__global__ __launch_bounds__(256) void gsum_ln0_kernel(
    const __half* __restrict__ g, const float* __restrict__ rns,
    const float* __restrict__ ln0g, const float* __restrict__ ln0b,
    __half* __restrict__ xn)
{
    int c = blockIdx.x * 256 + threadIdx.x;
    int node = c >> 4, ch0 = (c & 15) << 3;
    float s8[8] = {0,0,0,0,0,0,0,0};
#pragma unroll
    for (int k = 0; k < 9; ++k) {
        int4 v = *(const int4*)(g + (size_t)k * GSTRIDE + ((size_t)node << 7) + ch0);
        float2 f;
        f = __half22float2(*(__half2*)&v.x); s8[0] += f.x; s8[1] += f.y;
        f = __half22float2(*(__half2*)&v.y); s8[2] += f.x; s8[3] += f.y;
        f = __half22float2(*(__half2*)&v.z); s8[4] += f.x; s8[5] += f.y;
        f = __half22float2(*(__half2*)&v.w); s8[6] += f.x; s8[7] += f.y;
    }
    float sc = rns[node] * (1.0f / 9.0f);
#pragma unroll
    for (int i = 0; i < 8; ++i) s8[i] *= sc;

    float t = 0.f;
#pragma unroll
    for (int i = 0; i < 8; ++i) t += s8[i];
#pragma unroll
    for (int m = 1; m < 16; m <<= 1) t += __shfl_xor(t, m);
    float mean = t * (1.0f / 128.0f);
    float q = 0.f;
#pragma unroll
    for (int i = 0; i < 8; ++i) { s8[i] -= mean; q += s8[i] * s8[i]; }
#pragma unroll
    for (int m = 1; m < 16; m <<= 1) q += __shfl_xor(q, m);
    float rstd = rsqrtf(q * (1.0f / 128.0f) + 1e-5f);
    float4 ga = *(const float4*)(ln0g + ch0);
    float4 gA = *(const float4*)(ln0g + ch0 + 4);
    float4 ba = *(const float4*)(ln0b + ch0);
    float4 bA = *(const float4*)(ln0b + ch0 + 4);
    __half2 h0 = __float22half2_rn(make_float2(s8[0]*rstd*ga.x + ba.x, s8[1]*rstd*ga.y + ba.y));
    __half2 h1 = __float22half2_rn(make_float2(s8[2]*rstd*ga.z + ba.z, s8[3]*rstd*ga.w + ba.w));
    __half2 h2 = __float22half2_rn(make_float2(s8[4]*rstd*gA.x + bA.x, s8[5]*rstd*gA.y + bA.y));
    __half2 h3 = __float22half2_rn(make_float2(s8[6]*rstd*gA.z + bA.z, s8[7]*rstd*gA.w + bA.w));
    int4 w;
    w.x = *(int*)&h0; w.y = *(int*)&h1; w.z = *(int*)&h2; w.w = *(int*)&h3;
    *(int4*)(xn + ((size_t)node << 7) + ch0) = w;
}

// ---------------- mm2: y = ELU(xn@WpT+bp); LN1; logits = yn@WoT+bo; L2 norm ------
__global__ __launch_bounds__(256) void mm2_kernel(
    const __half* __restrict__ xn, const _Float16* __restrict__ WpT,
    const float* __restrict__ bp,
    const float* __restrict__ ln1g, const float* __restrict__ ln1b,
    const float* __restrict__ Wo, const float* __restrict__ bo,
    float* __restrict__ out)
{
    constexpr int LDB = 136;
    __shared__ _Float16 BT[128 * LDB];
    __shared__ _Float16 WoT[16 * LDB];
    __shared__ _Float16 YN[64 * LDB];
    int tid = threadIdx.x;
    for (int idx = tid * 8; idx < 128 * 128; idx += 256 * 8) {
        int n = idx >> 7, k = idx & 127;
        *(f16x8*)(&BT[n * LDB + k]) = *(const f16x8*)(&WpT[n * 128 + k]);
    }
    for (int idx = tid; idx < 2048; idx += 256) {
        int k = idx >> 4, c = idx & 15;
        WoT[c * LDB + k] = (_Float16)Wo[idx];
    }
    __syncthreads();

    int wave = tid >> 6, lane = tid & 63;
    int lr = lane & 15, lk = lane >> 4;
    int rb = blockIdx.x * 64 + wave * 16;

    f32x4 acc[8] = {};
    const __half* ap = xn + ((size_t)(rb + lr) << 7);
    for (int k0 = 0; k0 < 128; k0 += 32) {
        f16x8 a = *(const f16x8*)(ap + k0 + lk * 8);
#pragma unroll
        for (int t = 0; t < 8; ++t) {
            f16x8 bf = *(const f16x8*)(&BT[(t * 16 + lr) * LDB + k0 + lk * 8]);
            acc[t] = __builtin_amdgcn_mfma_f32_16x16x32_f16(a, bf, acc[t], 0, 0, 0);
        }
    }

    float bv[8], hg[8], hb[8];
#pragma unroll
    for (int t = 0; t < 8; ++t) {
        bv[t] = bp[t * 16 + lr];
        hg[t] = ln1g[t * 16 + lr];
        hb[t] = ln1b[t * 16 + lr];
    }
#pragma unroll
    for (int reg = 0; reg < 4; ++reg) {
        float y[8], S = 0.f;
#pragma unroll
        for (int t = 0; t < 8; ++t) {
            float v = acc[t][reg] + bv[t];
            v = v > 0.f ? v : (expf(v) - 1.f);
            y[t] = v; S += v;
        }
#pragma unroll
        for (int m = 1; m < 16; m <<= 1) S += __shfl_xor(S, m);
        float mean = S * (1.0f / 128.0f);
        float q = 0.f;
#pragma unroll
        for (int t = 0; t < 8; ++t) { y[t] -= mean; q += y[t] * y[t]; }
#pragma unroll
        for (int m = 1; m < 16; m <<= 1) q += __shfl_xor(q, m);
        float rstd = rsqrtf(q * (1.0f / 128.0f) + 1e-5f);
        int row_l = wave * 16 + lk * 4 + reg;
#pragma unroll
        for (int t = 0; t < 8; ++t)
            YN[row_l * LDB + t * 16 + lr] = (_Float16)(y[t] * rstd * hg[t] + hb[t]);
    }
    __syncthreads();

    f32x4 p = {};
    const _Float16* yrow = &YN[(wave * 16 + lr) * LDB];
    for (int k0 = 0; k0 < 128; k0 += 32) {
        f16x8 a = *(const f16x8*)(yrow + k0 + lk * 8);
        f16x8 bf = *(const f16x8*)(&WoT[lr * LDB + k0 + lk * 8]);
        p = __builtin_amdgcn_mfma_f32_16x16x32_f16(a, bf, p, 0, 0, 0);
    }
    float bol = bo[lr];
#pragma unroll
    for (int reg = 0; reg < 4; ++reg) {
        float logit = p[reg] + bol;
        float ss = logit * logit;
#pragma unroll
        for (int m = 1; m < 16; m <<= 1) ss += __shfl_xor(ss, m);
        float rinv = 1.0f / fmaxf(sqrtf(ss), 1e-12f);
        int row = rb + lk * 4 + reg;
        out[(size_t)row * 16 + lr] = logit * rinv;
    }
}

// ---------------- launch ----------------
extern "C" void kernel_launch(void* const* d_in, const int* in_sizes, int n_in,
                              void* d_out, int out_size, void* d_ws, size_t ws_size,
                              hipStream_t stream)
{
    const float* feat0 = (const float*)d_in[0];
    const float* feat1 = (const float*)d_in[1];
    const int*   src   = (const int*)d_in[2];
    const int*   dst   = (const int*)d_in[3];
    const float* W0    = (const float*)d_in[4];
    const float* b0    = (const float*)d_in[5];
    const float* W1    = (const float*)d_in[6];
    const float* b1    = (const float*)d_in[7];
    const float* ln0_g = (const float*)d_in[8];
    const float* ln0_b = (const float*)d_in[9];
    const float* ln1_g = (const float*)d_in[10];
    const float* ln1_b = (const float*)d_in[11];
    const float* Wp    = (const float*)d_in[12];
    const float* bp    = (const float*)d_in[13];
    const float* Wo    = (const float*)d_in[14];
    const float* bo    = (const float*)d_in[15];
    float* out = (float*)d_out;

    char* ws = (char*)d_ws;
    __half*         gbuf = (__half*)(ws + 0);           // 92,162,304
    unsigned*       ebuf = (unsigned*)(ws + 0);         // 2,688,000 (overlay; dead before projmm)
    float*          ns   = (float*)(ws + 92162304);
    float*          nsd  = (float*)(ws + 92322304);
    float*          rns  = (float*)(ws + 92482304);
    unsigned*       odeg = (unsigned*)(ws + 92642304);  // odeg+cnt+bptr contiguous
    unsigned*       cnt  = (unsigned*)(ws + 92802304);
    unsigned*       bptr = (unsigned*)(ws + 92962304);  // 8 uints
    unsigned short* csr  = (unsigned short*)(ws + 92962560); // 5,120,000
    __half*         xbuf = (__half*)(ws + 92962560);    // overlay (csr dead after hops)
    _Float16*       WT0  = (_Float16*)(ws + 103202560);
    _Float16*       WT1  = (_Float16*)(ws + 103268096);
    _Float16*       WpT  = (_Float16*)(ws + 103300864);
    // total ~103.3 MB

    wtrans_kernel<<<dim3(8, 4), 256, 0, stream>>>(W0, WT0, 256);
    wtrans_kernel<<<dim3(4, 4), 256, 0, stream>>>(W1, WT1, 128);
    wtrans_kernel<<<dim3(4, 4), 256, 0, stream>>>(Wp, WpT, 128);

    init_kernel<<<2048, 256, 0, stream>>>((unsigned*)csr, odeg, (unsigned*)gbuf);
    partition_kernel<<<NE / 256, 256, 0, stream>>>(src, dst, odeg, bptr, ebuf);
    scatter_kernel<<<2048, 256, 0, stream>>>(ebuf, bptr, cnt, csr);
    norm_kernel<<<(NN + 255) / 256, 256, 0, stream>>>(odeg, cnt, ns, nsd, rns, NN);

    projmm_kernel<256><<<(NT0 + 63) / 64, 256, 0, stream>>>(feat0, WT0, b0, ns, gbuf, 0, NT0);
    projmm_kernel<128><<<(NT0 + 63) / 64, 256, 0, stream>>>(feat1, WT1, b1, ns, gbuf, NT0, NT0);

    for (int h = 0; h < NHOPS; ++h) {
        hop_kernel<<<NN / 4, 256, 0, stream>>>(gbuf + (size_t)h * GSTRIDE,
                                               gbuf + (size_t)(h + 1) * GSTRIDE,
                                               cnt, csr, nsd);
    }

    gsum_ln0_kernel<<<2500, 256, 0, stream>>>(gbuf, rns, ln0_g, ln0_b, xbuf);
    mm2_kernel<<<NN / 64, 256, 0, stream>>>(xbuf, WpT, bp, ln1_g, ln1_b, Wo, bo, out);
}